// Round 21
// baseline (53.037 us; speedup 1.0000x reference)
//
#include <hip/hip_runtime.h>
#include <math.h>

#define BTOT 65536
#define NM   64
#define FIN  6
#define HID  64
#define FOUT 3

// d_out float32 layout (flat concat of reference tuple):
#define MO_OFF  0            // model_outputs (B,2,3) -> 393216
#define IDX_OFF 393216       // selection_indices (B) stored as float
#define LOG_OFF 458752       // selection_logits (B,64) = 1.0f
#define PRB_OFF 4653056      // selection_probabilities (B,64) = 1/64
#define OUT_END 8847360

#define LCAP  2048           // per-model dense list capacity (avg n = 1024)

typedef __attribute__((ext_vector_type(8))) short short8v;
typedef __attribute__((ext_vector_type(4))) float f32x4;
typedef __attribute__((ext_vector_type(4))) uint  u32x4;

union AB { uint u[4]; uint4 q; short8v v; };

static __device__ __forceinline__ uint pack_hi2(float a, float b) {
    return (__float_as_uint(b) & 0xFFFF0000u) | (__float_as_uint(a) >> 16);
}
static __device__ __forceinline__ float hi_part(float a) {
    return __uint_as_float(__float_as_uint(a) & 0xFFFF0000u);
}
// split 8 f32 -> hi frag + lo frag (bf16 truncation; lo catches residual).
static __device__ __forceinline__ void split8(const float (&e)[8], AB& hi, AB& lo) {
#pragma unroll
    for (int t = 0; t < 4; ++t) {
        float a = e[2 * t], b = e[2 * t + 1];
        hi.u[t] = pack_hi2(a, b);
        lo.u[t] = pack_hi2(a - hi_part(a), b - hi_part(b));
    }
}
// RTNE bf16 rounding, used for WEIGHTS (single-plane).
static __device__ __forceinline__ uint bf16rn(float x) {
    uint u = __float_as_uint(x);
    return (u + 0x7FFFu + ((u >> 16) & 1u)) >> 16;
}
static __device__ __forceinline__ void round8(const float (&e)[8], AB& w) {
#pragma unroll
    for (int t = 0; t < 4; ++t)
        w.u[t] = (bf16rn(e[2 * t + 1]) << 16) | bf16rn(e[2 * t]);
}
static __device__ __forceinline__ f32x4 mf(const AB& a, const AB& b, f32x4 c) {
    return __builtin_amdgcn_mfma_f32_16x16x32_bf16(a.v, b.v, c, 0, 0, 0);
}
// weight-row permutation: output feature o sits at (tile t, C-row i)
static __device__ __forceinline__ int permo(int t, int i) {
    return 32 * (i & 1) + 8 * (i >> 2) + 2 * t + ((i >> 1) & 1);
}

// A-frag sets: 0..3 = L0 tiles (K=8: 6 inputs + bias-as-k6); 4..27 = L1..L3
// (set = 4 + ly*8 + ks*4 + t); 28..29 = LF (ks 0..1).
#define NSETS 30
#define L1S   4
#define L2S   12
#define L3S   20
#define LFS   28

// --------- K1: 2048 blocks. [bid<256] index+sort (NORMAL stores -> L2/L3);
// --------- [256..319] weight conv; ALL blocks NT-fill the 33.5MB region. -----
__global__ void k_index_conv_fill(const float* __restrict__ in, float* __restrict__ out,
                                  int* __restrict__ sorted2, int* __restrict__ cnt,
                                  uint4* __restrict__ wsW4,
                                  const float* __restrict__ W0, const float* __restrict__ B0,
                                  const float* __restrict__ W1, const float* __restrict__ W2,
                                  const float* __restrict__ W3, const float* __restrict__ WF)
{
    __shared__ int lh[NM];
    const int tid = (int)threadIdx.x;
    const int bid = (int)blockIdx.x;

    if (bid < 256) {
        // ---- index + scatter ----
        if (tid < NM) lh[tid] = 0;
        __syncthreads();

        const int b = bid * 256 + tid;
        const float xv = in[b * 6 + 0];
        const float zv = in[b * 6 + 2];
        const float TWO_PI = 6.28318530717958647692f;
        float af = (float)atan2((double)zv, (double)xv);
        float t = fmodf(af + TWO_PI, TWO_PI) / TWO_PI * 64.0f;
        int idx = (int)floorf(t);
        idx = min(max(idx, 0), 63);

        out[IDX_OFF + b] = (float)idx;

        const int lrank = atomicAdd(&lh[idx], 1);      // LDS atomic only
        sorted2[(idx * 256 + bid) * 256 + lrank] = b;  // normal store -> L2/L3
        __syncthreads();
        if (tid < NM) cnt[tid * 256 + bid] = lh[tid];
    } else if (bid < 320) {
        // ---- weight conversion: one block per model ----
        const int mm = bid - 256;
        uint4* __restrict__ dst = wsW4 + mm * (NSETS * 64);

        // staging A: L1..L3, coalesced reads, permuted writes
        for (int job = tid; job < 3 * 512; job += 256) {
            const int ly = job >> 9;
            const int o  = (job >> 3) & 63;
            const int kc = job & 7;
            const float* Wl = (ly == 0) ? W1 : (ly == 1) ? W2 : W3;
            const float4* p = (const float4*)(Wl + mm * (HID * HID) + o * HID + kc * 8);
            float4 f0 = p[0], f1 = p[1];
            float e[8] = {f0.x, f0.y, f0.z, f0.w, f1.x, f1.y, f1.z, f1.w};
            const int t  = (o >> 1) & 3;
            const int cq = ((o >> 5) & 1) | ((o & 1) << 1) | (((o >> 3) & 3) << 2);
            const int ks = kc >> 2, gq = kc & 3;
            AB w;
            round8(e, w);
            dst[(L1S + ly * 8 + ks * 4 + t) * 64 + gq * 16 + cq] = w.q;
        }

        // staging B: small sets {0..3 (L0), 28..29 (LF)}
        for (int job = tid; job < 6 * 64; job += 256) {
            const int s = job >> 6, ln = job & 63;
            const int set = (s < 4) ? s : (s + 24);
            const int gq = ln >> 4, cq = ln & 15;
            float e[8];
            if (set < 4) {                                   // L0: K=6 +bias@k6
                const int o = permo(set, cq);
                if (gq == 0) {
                    const float* w = W0 + mm * (HID * FIN) + o * FIN;
#pragma unroll
                    for (int j = 0; j < 8; ++j)
                        e[j] = (j < FIN) ? w[j] : ((j == 6) ? B0[mm * HID + o] : 0.0f);
                } else {
#pragma unroll
                    for (int j = 0; j < 8; ++j) e[j] = 0.0f;
                }
            } else {                                         // LF (natural rows)
                const int ks = set - 28;
                if (cq < FOUT) {
                    const float* w = WF + mm * (FOUT * HID) + cq * HID + ks * 32 + gq * 8;
#pragma unroll
                    for (int j = 0; j < 8; ++j) e[j] = w[j];
                } else {
#pragma unroll
                    for (int j = 0; j < 8; ++j) e[j] = 0.0f;
                }
            }
            AB w;
            round8(e, w);
            dst[set * 64 + ln] = w.q;
        }
    }

    // ---- NT constant fill, all 2048 blocks grid-stride (full-machine BW) ----
    {
        u32x4* __restrict__ out4 = (u32x4*)out;
        const int start = LOG_OFF / 4;        // 114688
        const int split = PRB_OFF / 4;        // 1163264
        const u32x4 ones = {0x3F800000u, 0x3F800000u, 0x3F800000u, 0x3F800000u};
        const u32x4 prob = {0x3C800000u, 0x3C800000u, 0x3C800000u, 0x3C800000u};
#pragma unroll
        for (int k = 0; k < 4; ++k) {                  // 4 * 2048 * 256 = region
            const int i = start + k * 524288 + bid * 256 + tid;
            __builtin_nontemporal_store((i < split) ? ones : prob, (u32x4*)&out4[i]);
        }
    }
}

// --------- K1.5: compact buckets into dense listg[m][LCAP] + nlist[m] ---------
__global__ void k_compact(const int* __restrict__ cnt, const int* __restrict__ sorted2,
                          int* __restrict__ listg, int* __restrict__ nlist)
{
    __shared__ int wtot[4];
    __shared__ int wbase[4];
    const int m = (int)blockIdx.x;
    const int tid = (int)threadIdx.x;     // 256 threads = 4 waves
    const int wid = tid >> 6;
    const int lane = tid & 63;

    const int cval = cnt[m * 256 + tid];
    int isc = cval;
#pragma unroll
    for (int d = 1; d < 64; d <<= 1) {
        int y = __shfl_up(isc, d);
        if (lane >= d) isc += y;
    }
    if (lane == 63) wtot[wid] = isc;
    __syncthreads();
    {
        int run = 0;
#pragma unroll
        for (int w = 0; w < 4; ++w) { if (w == wid) wbase[wid] = run; run += wtot[w]; }
    }
    __syncthreads();
    if (tid == 0) nlist[m] = min(wtot[0] + wtot[1] + wtot[2] + wtot[3], LCAP);

    const int pos0 = wbase[wid] + (isc - cval);
    const int* src = sorted2 + (m * 256 + tid) * 256;
    for (int j = 0; j < cval; ++j) {
        const int p = pos0 + j;
        if (p < LCAP) listg[m * LCAP + p] = src[j];
    }
}

// ---------------- K2: lean MFMA MLP, 1024 threads (16 waves), 1 block/CU ------
// C = W·H^T convention: C row (g*4+r) = FEATURE, C col (c16) = SAMPLE.
// Output store on g==0 lanes: o[0..2] = features for sample bb (lane's c16).
__global__ __launch_bounds__(1024, 4) void k_mlp(
    const float* __restrict__ in,
    const float* __restrict__ B1, const float* __restrict__ B2,
    const float* __restrict__ B3, const float* __restrict__ BF,
    const uint4* __restrict__ wsW4,
    const int* __restrict__ listg, const int* __restrict__ nlist,
    float* __restrict__ out)
{
    __shared__ uint bhS[NSETS][64][4];          // 30720 B (single weight plane)

    const int m = blockIdx.x;
    const int yy = (int)blockIdx.y;             // 0..3
    const int tid = (int)threadIdx.x;
    const int wid = tid >> 6;                   // 0..15
    const int lane = tid & 63;
    const int g = lane >> 4;
    const int c16 = lane & 15;

    const int n = nlist[m];

    // ---- prefetch tile-0 sample id + x (issues before the staging barrier) --
    const int ti0 = yy * 16 + wid;
    int b0 = 0;
    float e0[8] = {0.0f, 0.0f, 0.0f, 0.0f, 0.0f, 0.0f, 1.0f, 0.0f};
    const bool have0 = (ti0 * 16 < n);
    if (have0) {
        int s = ti0 * 16 + c16; if (s >= n) s = n - 1;
        b0 = listg[m * LCAP + s];
        if (g == 0) {
            const float* xp = in + b0 * 6;
#pragma unroll
            for (int j = 0; j < FIN; ++j) e0[j] = xp[j];
        }
    }

    // ---- staging: pure coalesced copy of pre-fragmented weights ----
    {
        const uint4* src = wsW4 + m * (NSETS * 64);
        for (int job = tid; job < NSETS * 64; job += 1024) {
            uint4 w = src[job];
            *(uint4*)&bhS[job >> 6][job & 63][0] = w;
        }
    }
    __syncthreads();

    // hoist LF A-frags (loop-invariant, single plane)
    AB lf[2];
#pragma unroll
    for (int ks = 0; ks < 2; ++ks)
        lf[ks].q = *(const uint4*)&bhS[LFS + ks][lane][0];
    const float bf0 = BF[m * FOUT + 0];
    const float bf1 = BF[m * FOUT + 1];
    const float bf2 = BF[m * FOUT + 2];

    for (int ti = ti0; ti * 16 < n; ti += 64) {
        int bb;
        const int s = ti * 16 + c16;
        const bool act = (s < n);
        float e[8] = {0.0f, 0.0f, 0.0f, 0.0f, 0.0f, 0.0f, 1.0f, 0.0f};
        if (ti == ti0) {
            bb = b0;
            if (g == 0) {
#pragma unroll
                for (int j = 0; j < FIN; ++j) e[j] = e0[j];
            }
        } else {
            int sc = act ? s : (n - 1);
            bb = listg[m * LCAP + sc];
            if (g == 0) {
                const float* xp = in + bb * 6;
#pragma unroll
                for (int j = 0; j < FIN; ++j) e[j] = xp[j];
            }
        }

        // ---- L0: B = X^T (samples in columns, hi/lo), bias folded at k=6 ----
        AB xh, xl;
        if (g == 0) {
            split8(e, xh, xl);
        } else {
#pragma unroll
            for (int t = 0; t < 4; ++t) { xh.u[t] = 0u; xl.u[t] = 0u; }
        }
        f32x4 acc[4];
#pragma unroll
        for (int t = 0; t < 4; ++t) {
            AB ah;
            ah.q = *(const uint4*)&bhS[t][lane][0];
            f32x4 cc = {0.0f, 0.0f, 0.0f, 0.0f};
            cc = mf(ah, xh, cc); cc = mf(ah, xl, cc);
            acc[t] = cc;
        }

        AB bh[2], bl[2];
        // H0 frag: relu(acc) (L0 bias folded), feature f=ks*32+g*8+jj lives at
        // acc[jj>>1][2*(jj&1)+ks] in THIS lane (permo identity).
#pragma unroll
        for (int ks = 0; ks < 2; ++ks) {
            float ee[8];
#pragma unroll
            for (int jj = 0; jj < 8; ++jj)
                ee[jj] = fmaxf(acc[jj >> 1][2 * (jj & 1) + ks], 0.0f);
            split8(ee, bh[ks], bl[ks]);
        }

#define LAYERX(SET0)                                                          \
        _Pragma("unroll")                                                     \
        for (int ks = 0; ks < 2; ++ks)                                        \
        _Pragma("unroll")                                                     \
        for (int t = 0; t < 4; ++t) {                                         \
            AB ah;                                                            \
            ah.q = *(const uint4*)&bhS[(SET0) + ks * 4 + t][lane][0];          \
            f32x4 cc = (ks == 0) ? f32x4{0.0f, 0.0f, 0.0f, 0.0f} : acc[t];    \
            cc = mf(ah, bh[ks], cc);                                          \
            cc = mf(ah, bl[ks], cc);                                          \
            acc[t] = cc;                                                      \
        }

#define BUILDF(BPTR)                                                          \
        _Pragma("unroll")                                                     \
        for (int ks = 0; ks < 2; ++ks) {                                      \
            const float4* bp = (const float4*)((BPTR) + ks * 32 + g * 8);     \
            float4 q0 = bp[0], q1 = bp[1];                                    \
            float bb8[8] = {q0.x, q0.y, q0.z, q0.w, q1.x, q1.y, q1.z, q1.w};  \
            float ee[8];                                                      \
            _Pragma("unroll")                                                 \
            for (int jj = 0; jj < 8; ++jj)                                    \
                ee[jj] = fmaxf(acc[jj >> 1][2 * (jj & 1) + ks] + bb8[jj], 0.0f);\
            split8(ee, bh[ks], bl[ks]);                                       \
        }

#define LFINX(PASS)                                                           \
        {                                                                     \
            f32x4 o = {bf0, bf1, bf2, 0.0f};                                  \
            _Pragma("unroll")                                                 \
            for (int ks = 0; ks < 2; ++ks) {                                  \
                o = mf(lf[ks], bh[ks], o);                                    \
                o = mf(lf[ks], bl[ks], o);                                    \
            }                                                                 \
            if (g == 0 && act) {                                              \
                float* p = out + MO_OFF + bb * 6 + (PASS) * 3;                \
                p[0] = o[0]; p[1] = o[1]; p[2] = o[2];                        \
            }                                                                 \
        }

        LAYERX(L1S);           // acc = W1·(H0h+H0l)
        BUILDF(B1 + m * HID);  // h1 frag (bias b1 + relu)
        LFINX(0);              // output after layer 1 (uses h1)
        LAYERX(L2S);           // acc = W2·H1
        BUILDF(B2 + m * HID);  // h2 frag
        LAYERX(L3S);           // acc = W3·H2
        BUILDF(B3 + m * HID);  // h3 frag
        LFINX(1);              // final output (uses h3)
    }
}

extern "C" void kernel_launch(void* const* d_in, const int* in_sizes, int n_in,
                              void* d_out, int out_size, void* d_ws, size_t ws_size,
                              hipStream_t stream)
{
    const float* in = (const float*)d_in[0];
    const float* W0 = (const float*)d_in[1];
    const float* B0 = (const float*)d_in[2];
    const float* W1 = (const float*)d_in[3];
    const float* B1 = (const float*)d_in[4];
    const float* W2 = (const float*)d_in[5];
    const float* B2 = (const float*)d_in[6];
    const float* W3 = (const float*)d_in[7];
    const float* B3 = (const float*)d_in[8];
    const float* WF = (const float*)d_in[9];
    const float* BF = (const float*)d_in[10];
    float* out = (float*)d_out;

    int*  sorted2 = (int*)d_ws;                   // [64][256][256] ints = 16.8 MB
    int*  cnt     = sorted2 + NM * 256 * 256;     // [64][256] ints = 64 KB
    uint4* wsW4   = (uint4*)(cnt + NM * 256);     // [64][30][64] uint4 = 1.97 MB
    int*  listg   = (int*)(wsW4 + NM * NSETS * 64); // [64][2048] ints = 512 KB
    int*  nlist   = listg + NM * LCAP;            // 64 ints

    k_index_conv_fill<<<2048, 256, 0, stream>>>(in, out, sorted2, cnt, wsW4,
                                                W0, B0, W1, W2, W3, WF);
    k_compact<<<NM, 256, 0, stream>>>(cnt, sorted2, listg, nlist);
    k_mlp<<<dim3(NM, 4), 1024, 0, stream>>>(in, B1, B2, B3, BF, wsW4,
                                            listg, nlist, out);
}

// Round 22
// 28.981 us; speedup vs baseline: 1.8301x; 1.8301x over previous
//
#include <hip/hip_runtime.h>
#include <math.h>

#define BTOT 65536
#define NM   64
#define FIN  6
#define HID  64
#define FOUT 3

// d_out float32 layout (flat concat of reference tuple):
#define MO_OFF  0            // model_outputs (B,2,3) -> 393216
#define IDX_OFF 393216       // selection_indices (B) stored as float
#define LOG_OFF 458752       // selection_logits (B,64) = 1.0f
#define PRB_OFF 4653056      // selection_probabilities (B,64) = 1/64
#define OUT_END 8847360

#define LCAP  2048           // per-model dense list capacity (avg n = 1024)

typedef __attribute__((ext_vector_type(8))) short short8v;
typedef __attribute__((ext_vector_type(4))) float f32x4;
typedef __attribute__((ext_vector_type(4))) uint  u32x4;

union AB { uint u[4]; uint4 q; short8v v; };

static __device__ __forceinline__ uint pack_hi2(float a, float b) {
    return (__float_as_uint(b) & 0xFFFF0000u) | (__float_as_uint(a) >> 16);
}
static __device__ __forceinline__ float hi_part(float a) {
    return __uint_as_float(__float_as_uint(a) & 0xFFFF0000u);
}
// split 8 f32 -> hi frag + lo frag (bf16 truncation; lo catches residual).
static __device__ __forceinline__ void split8(const float (&e)[8], AB& hi, AB& lo) {
#pragma unroll
    for (int t = 0; t < 4; ++t) {
        float a = e[2 * t], b = e[2 * t + 1];
        hi.u[t] = pack_hi2(a, b);
        lo.u[t] = pack_hi2(a - hi_part(a), b - hi_part(b));
    }
}
// RTNE bf16 rounding, used for WEIGHTS (single-plane).
static __device__ __forceinline__ uint bf16rn(float x) {
    uint u = __float_as_uint(x);
    return (u + 0x7FFFu + ((u >> 16) & 1u)) >> 16;
}
static __device__ __forceinline__ void round8(const float (&e)[8], AB& w) {
#pragma unroll
    for (int t = 0; t < 4; ++t)
        w.u[t] = (bf16rn(e[2 * t + 1]) << 16) | bf16rn(e[2 * t]);
}
static __device__ __forceinline__ f32x4 mf(const AB& a, const AB& b, f32x4 c) {
    return __builtin_amdgcn_mfma_f32_16x16x32_bf16(a.v, b.v, c, 0, 0, 0);
}
// weight-row permutation: output feature o sits at (tile t, C-row i)
static __device__ __forceinline__ int permo(int t, int i) {
    return 32 * (i & 1) + 8 * (i >> 2) + 2 * t + ((i >> 1) & 1);
}

// A-frag sets: 0..3 = L0 tiles (K=8: 6 inputs + bias-as-k6); 4..27 = L1..L3
// (set = 4 + ly*8 + ks*4 + t); 28..29 = LF (ks 0..1).
#define NSETS 30
#define L1S   4
#define L2S   12
#define L3S   20
#define LFS   28

// --------- K1: 2048 blocks. [bid<256] index+sort (NORMAL stores -> L2/L3);
// --------- [256..319] weight conv; ALL blocks NT-fill the 33.5MB region. -----
__global__ void k_index_conv_fill(const float* __restrict__ in, float* __restrict__ out,
                                  int* __restrict__ sorted2, int* __restrict__ cnt,
                                  uint4* __restrict__ wsW4,
                                  const float* __restrict__ W0, const float* __restrict__ B0,
                                  const float* __restrict__ W1, const float* __restrict__ W2,
                                  const float* __restrict__ W3, const float* __restrict__ WF)
{
    __shared__ int lh[NM];
    const int tid = (int)threadIdx.x;
    const int bid = (int)blockIdx.x;

    if (bid < 256) {
        // ---- index + scatter ----
        if (tid < NM) lh[tid] = 0;
        __syncthreads();

        const int b = bid * 256 + tid;
        const float xv = in[b * 6 + 0];
        const float zv = in[b * 6 + 2];
        const float TWO_PI = 6.28318530717958647692f;
        float af = (float)atan2((double)zv, (double)xv);
        float t = fmodf(af + TWO_PI, TWO_PI) / TWO_PI * 64.0f;
        int idx = (int)floorf(t);
        idx = min(max(idx, 0), 63);

        out[IDX_OFF + b] = (float)idx;

        const int lrank = atomicAdd(&lh[idx], 1);      // LDS atomic only
        sorted2[(idx * 256 + bid) * 256 + lrank] = b;  // normal store -> L2/L3
        __syncthreads();
        if (tid < NM) cnt[tid * 256 + bid] = lh[tid];
    } else if (bid < 320) {
        // ---- weight conversion: one block per model ----
        const int mm = bid - 256;
        uint4* __restrict__ dst = wsW4 + mm * (NSETS * 64);

        // staging A: L1..L3, coalesced reads, permuted writes
        for (int job = tid; job < 3 * 512; job += 256) {
            const int ly = job >> 9;
            const int o  = (job >> 3) & 63;
            const int kc = job & 7;
            const float* Wl = (ly == 0) ? W1 : (ly == 1) ? W2 : W3;
            const float4* p = (const float4*)(Wl + mm * (HID * HID) + o * HID + kc * 8);
            float4 f0 = p[0], f1 = p[1];
            float e[8] = {f0.x, f0.y, f0.z, f0.w, f1.x, f1.y, f1.z, f1.w};
            const int t  = (o >> 1) & 3;
            const int cq = ((o >> 5) & 1) | ((o & 1) << 1) | (((o >> 3) & 3) << 2);
            const int ks = kc >> 2, gq = kc & 3;
            AB w;
            round8(e, w);
            dst[(L1S + ly * 8 + ks * 4 + t) * 64 + gq * 16 + cq] = w.q;
        }

        // staging B: small sets {0..3 (L0), 28..29 (LF)}
        for (int job = tid; job < 6 * 64; job += 256) {
            const int s = job >> 6, ln = job & 63;
            const int set = (s < 4) ? s : (s + 24);
            const int gq = ln >> 4, cq = ln & 15;
            float e[8];
            if (set < 4) {                                   // L0: K=6 +bias@k6
                const int o = permo(set, cq);
                if (gq == 0) {
                    const float* w = W0 + mm * (HID * FIN) + o * FIN;
#pragma unroll
                    for (int j = 0; j < 8; ++j)
                        e[j] = (j < FIN) ? w[j] : ((j == 6) ? B0[mm * HID + o] : 0.0f);
                } else {
#pragma unroll
                    for (int j = 0; j < 8; ++j) e[j] = 0.0f;
                }
            } else {                                         // LF (natural rows)
                const int ks = set - 28;
                if (cq < FOUT) {
                    const float* w = WF + mm * (FOUT * HID) + cq * HID + ks * 32 + gq * 8;
#pragma unroll
                    for (int j = 0; j < 8; ++j) e[j] = w[j];
                } else {
#pragma unroll
                    for (int j = 0; j < 8; ++j) e[j] = 0.0f;
                }
            }
            AB w;
            round8(e, w);
            dst[set * 64 + ln] = w.q;
        }
    }

    // ---- NT constant fill, all 2048 blocks grid-stride (full-machine BW) ----
    {
        u32x4* __restrict__ out4 = (u32x4*)out;
        const int start = LOG_OFF / 4;        // 114688
        const int split = PRB_OFF / 4;        // 1163264
        const u32x4 ones = {0x3F800000u, 0x3F800000u, 0x3F800000u, 0x3F800000u};
        const u32x4 prob = {0x3C800000u, 0x3C800000u, 0x3C800000u, 0x3C800000u};
#pragma unroll
        for (int k = 0; k < 4; ++k) {                  // 4 * 2048 * 256 = region
            const int i = start + k * 524288 + bid * 256 + tid;
            __builtin_nontemporal_store((i < split) ? ones : prob, (u32x4*)&out4[i]);
        }
    }
}

// --------- K1.5: compact buckets into dense listg[m][LCAP] + nlist[m] ---------
__global__ void k_compact(const int* __restrict__ cnt, const int* __restrict__ sorted2,
                          int* __restrict__ listg, int* __restrict__ nlist)
{
    __shared__ int wtot[4];
    __shared__ int wbase[4];
    const int m = (int)blockIdx.x;
    const int tid = (int)threadIdx.x;     // 256 threads = 4 waves
    const int wid = tid >> 6;
    const int lane = tid & 63;

    const int cval = cnt[m * 256 + tid];
    int isc = cval;
#pragma unroll
    for (int d = 1; d < 64; d <<= 1) {
        int y = __shfl_up(isc, d);
        if (lane >= d) isc += y;
    }
    if (lane == 63) wtot[wid] = isc;
    __syncthreads();
    {
        int run = 0;
#pragma unroll
        for (int w = 0; w < 4; ++w) { if (w == wid) wbase[wid] = run; run += wtot[w]; }
    }
    __syncthreads();
    if (tid == 0) nlist[m] = min(wtot[0] + wtot[1] + wtot[2] + wtot[3], LCAP);

    const int pos0 = wbase[wid] + (isc - cval);
    const int* src = sorted2 + (m * 256 + tid) * 256;
    for (int j = 0; j < cval; ++j) {
        const int p = pos0 + j;
        if (p < LCAP) listg[m * LCAP + p] = src[j];
    }
}

// ---------------- K2: lean MFMA MLP (dense list, prefetched tile-0) -----------
// C = W·H^T convention: C row (g*4+r) = FEATURE, C col (c16) = SAMPLE.
// Output store on g==0 lanes: o[0..2] = features for sample bb (lane's c16).
__global__ __launch_bounds__(512, 2) void k_mlp(
    const float* __restrict__ in,
    const float* __restrict__ B1, const float* __restrict__ B2,
    const float* __restrict__ B3, const float* __restrict__ BF,
    const uint4* __restrict__ wsW4,
    const int* __restrict__ listg, const int* __restrict__ nlist,
    float* __restrict__ out)
{
    __shared__ uint bhS[NSETS][64][4];          // 30720 B (single weight plane)

    const int m = blockIdx.x;
    const int yy = (int)blockIdx.y;             // 0..7
    const int tid = (int)threadIdx.x;
    const int wid = tid >> 6;
    const int lane = tid & 63;
    const int g = lane >> 4;
    const int c16 = lane & 15;

    const int n = nlist[m];

    // ---- prefetch tile-0 sample id + x (issues before the staging barrier) --
    const int ti0 = yy * 8 + wid;
    int b0 = 0;
    float e0[8] = {0.0f, 0.0f, 0.0f, 0.0f, 0.0f, 0.0f, 1.0f, 0.0f};
    const bool have0 = (ti0 * 16 < n);
    if (have0) {
        int s = ti0 * 16 + c16; if (s >= n) s = n - 1;
        b0 = listg[m * LCAP + s];
        if (g == 0) {
            const float* xp = in + b0 * 6;
#pragma unroll
            for (int j = 0; j < FIN; ++j) e0[j] = xp[j];
        }
    }

    // ---- staging: pure coalesced copy of pre-fragmented weights ----
    {
        const uint4* src = wsW4 + m * (NSETS * 64);
        for (int job = tid; job < NSETS * 64; job += 512) {
            uint4 w = src[job];
            *(uint4*)&bhS[job >> 6][job & 63][0] = w;
        }
    }
    __syncthreads();

    // hoist LF A-frags (loop-invariant, single plane)
    AB lf[2];
#pragma unroll
    for (int ks = 0; ks < 2; ++ks)
        lf[ks].q = *(const uint4*)&bhS[LFS + ks][lane][0];
    const float bf0 = BF[m * FOUT + 0];
    const float bf1 = BF[m * FOUT + 1];
    const float bf2 = BF[m * FOUT + 2];

    for (int ti = ti0; ti * 16 < n; ti += 64) {
        int bb;
        const int s = ti * 16 + c16;
        const bool act = (s < n);
        float e[8] = {0.0f, 0.0f, 0.0f, 0.0f, 0.0f, 0.0f, 1.0f, 0.0f};
        if (ti == ti0) {
            bb = b0;
            if (g == 0) {
#pragma unroll
                for (int j = 0; j < FIN; ++j) e[j] = e0[j];
            }
        } else {
            int sc = act ? s : (n - 1);
            bb = listg[m * LCAP + sc];
            if (g == 0) {
                const float* xp = in + bb * 6;
#pragma unroll
                for (int j = 0; j < FIN; ++j) e[j] = xp[j];
            }
        }

        // ---- L0: B = X^T (samples in columns, hi/lo), bias folded at k=6 ----
        AB xh, xl;
        if (g == 0) {
            split8(e, xh, xl);
        } else {
#pragma unroll
            for (int t = 0; t < 4; ++t) { xh.u[t] = 0u; xl.u[t] = 0u; }
        }
        f32x4 acc[4];
#pragma unroll
        for (int t = 0; t < 4; ++t) {
            AB ah;
            ah.q = *(const uint4*)&bhS[t][lane][0];
            f32x4 cc = {0.0f, 0.0f, 0.0f, 0.0f};
            cc = mf(ah, xh, cc); cc = mf(ah, xl, cc);
            acc[t] = cc;
        }

        AB bh[2], bl[2];
        // H0 frag: relu(acc) (L0 bias folded), feature f=ks*32+g*8+jj lives at
        // acc[jj>>1][2*(jj&1)+ks] in THIS lane (permo identity).
#pragma unroll
        for (int ks = 0; ks < 2; ++ks) {
            float ee[8];
#pragma unroll
            for (int jj = 0; jj < 8; ++jj)
                ee[jj] = fmaxf(acc[jj >> 1][2 * (jj & 1) + ks], 0.0f);
            split8(ee, bh[ks], bl[ks]);
        }

#define LAYERX(SET0)                                                          \
        _Pragma("unroll")                                                     \
        for (int ks = 0; ks < 2; ++ks)                                        \
        _Pragma("unroll")                                                     \
        for (int t = 0; t < 4; ++t) {                                         \
            AB ah;                                                            \
            ah.q = *(const uint4*)&bhS[(SET0) + ks * 4 + t][lane][0];          \
            f32x4 cc = (ks == 0) ? f32x4{0.0f, 0.0f, 0.0f, 0.0f} : acc[t];    \
            cc = mf(ah, bh[ks], cc);                                          \
            cc = mf(ah, bl[ks], cc);                                          \
            acc[t] = cc;                                                      \
        }

#define BUILDF(BPTR)                                                          \
        _Pragma("unroll")                                                     \
        for (int ks = 0; ks < 2; ++ks) {                                      \
            const float4* bp = (const float4*)((BPTR) + ks * 32 + g * 8);     \
            float4 q0 = bp[0], q1 = bp[1];                                    \
            float bb8[8] = {q0.x, q0.y, q0.z, q0.w, q1.x, q1.y, q1.z, q1.w};  \
            float ee[8];                                                      \
            _Pragma("unroll")                                                 \
            for (int jj = 0; jj < 8; ++jj)                                    \
                ee[jj] = fmaxf(acc[jj >> 1][2 * (jj & 1) + ks] + bb8[jj], 0.0f);\
            split8(ee, bh[ks], bl[ks]);                                       \
        }

#define LFINX(PASS)                                                           \
        {                                                                     \
            f32x4 o = {bf0, bf1, bf2, 0.0f};                                  \
            _Pragma("unroll")                                                 \
            for (int ks = 0; ks < 2; ++ks) {                                  \
                o = mf(lf[ks], bh[ks], o);                                    \
                o = mf(lf[ks], bl[ks], o);                                    \
            }                                                                 \
            if (g == 0 && act) {                                              \
                float* p = out + MO_OFF + bb * 6 + (PASS) * 3;                \
                p[0] = o[0]; p[1] = o[1]; p[2] = o[2];                        \
            }                                                                 \
        }

        LAYERX(L1S);           // acc = W1·(H0h+H0l)
        BUILDF(B1 + m * HID);  // h1 frag (bias b1 + relu)
        LFINX(0);              // output after layer 1 (uses h1)
        LAYERX(L2S);           // acc = W2·H1
        BUILDF(B2 + m * HID);  // h2 frag
        LAYERX(L3S);           // acc = W3·H2
        BUILDF(B3 + m * HID);  // h3 frag
        LFINX(1);              // final output (uses h3)
    }
}

extern "C" void kernel_launch(void* const* d_in, const int* in_sizes, int n_in,
                              void* d_out, int out_size, void* d_ws, size_t ws_size,
                              hipStream_t stream)
{
    const float* in = (const float*)d_in[0];
    const float* W0 = (const float*)d_in[1];
    const float* B0 = (const float*)d_in[2];
    const float* W1 = (const float*)d_in[3];
    const float* B1 = (const float*)d_in[4];
    const float* W2 = (const float*)d_in[5];
    const float* B2 = (const float*)d_in[6];
    const float* W3 = (const float*)d_in[7];
    const float* B3 = (const float*)d_in[8];
    const float* WF = (const float*)d_in[9];
    const float* BF = (const float*)d_in[10];
    float* out = (float*)d_out;

    int*  sorted2 = (int*)d_ws;                   // [64][256][256] ints = 16.8 MB
    int*  cnt     = sorted2 + NM * 256 * 256;     // [64][256] ints = 64 KB
    uint4* wsW4   = (uint4*)(cnt + NM * 256);     // [64][30][64] uint4 = 1.97 MB
    int*  listg   = (int*)(wsW4 + NM * NSETS * 64); // [64][2048] ints = 512 KB
    int*  nlist   = listg + NM * LCAP;            // 64 ints

    k_index_conv_fill<<<2048, 256, 0, stream>>>(in, out, sorted2, cnt, wsW4,
                                                W0, B0, W1, W2, W3, WF);
    k_compact<<<NM, 256, 0, stream>>>(cnt, sorted2, listg, nlist);
    k_mlp<<<dim3(NM, 8), 512, 0, stream>>>(in, B1, B2, B3, BF, wsW4,
                                           listg, nlist, out);
}